// Round 6
// baseline (406.460 us; speedup 1.0000x reference)
//
#include <hip/hip_runtime.h>
#include <math.h>

#define NB 4
#define NC 12
#define NM 2
#define NN 320
#define NHW (NN*NN)
#define NBC (NB*NC)
#define CG_TOL 1e-6f
#define NITER 10
#define CBLK 400   // blocks per batch for update1 (102400/256)
#define QBLK 320   // pq partials per batch (one per h-row)
#define CPG 3      // coils per group in deep fft kernels
#define NG  4      // groups (NC/CPG)

#define TWO_PI_F 6.28318530717958647692f

typedef float2 c32;

__device__ __forceinline__ c32 cmul(c32 a, c32 b){ return make_float2(a.x*b.x - a.y*b.y, a.x*b.y + a.y*b.x); }
__device__ __forceinline__ c32 cmulj(c32 a, c32 b){ return make_float2(a.x*b.x + a.y*b.y, a.x*b.y - a.y*b.x); } // conj(a)*b
__device__ __forceinline__ c32 cadd(c32 a, c32 b){ return make_float2(a.x+b.x, a.y+b.y); }
__device__ __forceinline__ c32 csub(c32 a, c32 b){ return make_float2(a.x-b.x, a.y-b.y); }
__device__ __forceinline__ c32 cscale(c32 a, float s){ return make_float2(a.x*s, a.y*s); }

// multiply a by (CONJ ? conj(t) : t)
template<bool CONJ>
__device__ __forceinline__ c32 twmul(c32 a, c32 t){
  return CONJ ? make_float2(a.x*t.x + a.y*t.y, a.y*t.x - a.x*t.y)
              : make_float2(a.x*t.x - a.y*t.y, a.y*t.x + a.x*t.y);
}

__device__ __forceinline__ float wave_reduce_f(float v) {
  #pragma unroll
  for (int off = 32; off >= 1; off >>= 1) v += __shfl_xor(v, off, 64);
  return v;
}
__device__ __forceinline__ c32 wave_reduce_c(c32 v) {
  #pragma unroll
  for (int off = 32; off >= 1; off >>= 1) {
    v.x += __shfl_xor(v.x, off, 64);
    v.y += __shfl_xor(v.y, off, 64);
  }
  return v;
}

// T320[j] = cis(2*pi*j/320), j=0..255 ; T64[k] = cis(2*pi*k/64), k=0..31.
__global__ __launch_bounds__(256)
void twiddle_init(c32* __restrict__ T320, c32* __restrict__ T64)
{
  const int t = threadIdx.x;
  {
    float s, c; sincosf(TWO_PI_F * (float)t / 320.f, &s, &c);
    T320[t] = make_float2(c, s);
  }
  if (t < 32) {
    float s, c; sincosf(TWO_PI_F * (float)t / 64.f, &s, &c);
    T64[t] = make_float2(c, s);
  }
}

template<bool FWD>
__device__ __forceinline__ void radix5(c32 V[5]) {
  constexpr float C1 = 0.30901699437494745f;
  constexpr float S1 = 0.9510565162951535f;
  constexpr float C2 = -0.8090169943749475f;
  constexpr float S2 = 0.5877852522924731f;
  constexpr float sg = FWD ? -1.f : 1.f;
  const c32 w1 = make_float2(C1,  sg*S1);
  const c32 w2 = make_float2(C2,  sg*S2);
  const c32 w3 = make_float2(C2, -sg*S2);
  const c32 w4 = make_float2(C1, -sg*S1);
  c32 v0=V[0], v1=V[1], v2=V[2], v3=V[3], v4=V[4];
  V[0] = cadd(cadd(v0, v1), cadd(cadd(v2, v3), v4));
  V[1] = cadd(v0, cadd(cadd(cmul(v1,w1), cmul(v2,w2)), cadd(cmul(v3,w3), cmul(v4,w4))));
  V[2] = cadd(v0, cadd(cadd(cmul(v1,w2), cmul(v2,w4)), cadd(cmul(v3,w1), cmul(v4,w3))));
  V[3] = cadd(v0, cadd(cadd(cmul(v1,w3), cmul(v2,w1)), cadd(cmul(v3,w4), cmul(v4,w2))));
  V[4] = cadd(v0, cadd(cadd(cmul(v1,w4), cmul(v2,w3)), cadd(cmul(v3,w2), cmul(v4,w1))));
}

// Forward-structured 320-pt FFT: A[j]=x[lane+64j] (natural) -> A[k] = X[k+5*rev6(lane)] (scrambled).
// FWD=true: DFT (conj twiddles); FWD=false: unnormalized IDFT (x320).
template<bool FWD>
__device__ __forceinline__ void fft320_one(c32 A[5], const c32 ct[4], const c32 tw[6], int lane)
{
  radix5<FWD>(A);
  #pragma unroll
  for (int k = 1; k < 5; ++k) A[k] = twmul<FWD>(A[k], ct[k-1]);
  #pragma unroll
  for (int s = 0; s < 6; ++s) {
    const int m = 32 >> s;
    const c32 w = tw[s];
    const bool up = (lane & m) != 0;
    c32 o[5];
    #pragma unroll
    for (int k = 0; k < 5; ++k) { o[k].x = __shfl_xor(A[k].x, m, 64); o[k].y = __shfl_xor(A[k].y, m, 64); }
    #pragma unroll
    for (int k = 0; k < 5; ++k) {
      c32 lo = cadd(A[k], o[k]);
      c32 hi = twmul<FWD>(csub(o[k], A[k]), w);
      A[k] = up ? hi : lo;
    }
  }
}

// Inverse DIT consuming SCRAMBLED input (exact network reversal of fft320_one<true>):
// A[k] = X[k+5*rev6(lane)] -> A[j] = 320*x[lane+64j] (natural). Unnormalized.
__device__ __forceinline__ void ifft320_dit(c32 A[5], const c32 ct[4], const c32 tw[6], int lane)
{
  #pragma unroll
  for (int s = 5; s >= 0; --s) {
    const int m = 32 >> s;
    const c32 w = tw[s];
    const bool up = (lane & m) != 0;
    #pragma unroll
    for (int k = 0; k < 5; ++k) {
      c32 t = up ? twmul<false>(A[k], w) : A[k];   // hi lane: own * w^{-1}
      c32 o; o.x = __shfl_xor(t.x, m, 64); o.y = __shfl_xor(t.y, m, 64);
      A[k] = up ? csub(o, t) : cadd(t, o);
    }
  }
  #pragma unroll
  for (int k = 1; k < 5; ++k) A[k] = twmul<false>(A[k], ct[k-1]);
  radix5<false>(A);
}

#define LOAD_TWIDDLES \
  c32 ct[4], tw[6]; \
  _Pragma("unroll") for (int k_ = 0; k_ < 4; ++k_) ct[k_] = T320[(k_ + 1) * lane]; \
  _Pragma("unroll") for (int s_ = 0; s_ < 6; ++s_) tw[s_] = T64[(lane & ((32 >> s_) - 1)) << s_];

// ---- setup pass 1: (y*mask) IFFT along contiguous k_w, transposed write [bc][w][kh] ----
__global__ __launch_bounds__(512)
void setup_mask_ifft(const c32* __restrict__ in, c32* __restrict__ out,
                     const float* __restrict__ mask,
                     const c32* __restrict__ T320, const c32* __restrict__ T64)
{
  __shared__ c32 tile[8][NN + 2];
  const int tid = threadIdx.x, lane = tid & 63, wv = tid >> 6;
  const int bc = blockIdx.y, r0 = blockIdx.x * 8;
  LOAD_TWIDDLES
  const int rv6 = __brev((unsigned)lane) >> 26;
  const int row = r0 + wv;
  c32 A[5];
  #pragma unroll
  for (int j = 0; j < 5; ++j) {
    const size_t idx = ((size_t)bc * NN + row) * NN + lane + 64*j;
    A[j] = cscale(in[idx], mask[idx]);
  }
  fft320_one<false>(A, ct, tw, lane);
  #pragma unroll
  for (int k = 0; k < 5; ++k) tile[wv][k + 5*rv6] = A[k];
  __syncthreads();
  #pragma unroll
  for (int it = 0; it < 5; ++it) {
    const int idx = it * 512 + tid, u = idx >> 3, d = idx & 7;
    out[((size_t)bc * NN + u) * NN + (r0 + d)] = tile[d][u];
  }
}

// ---- setup pass 2 fused with init: IFFT along contiguous k_h (input [bc][w][kh]),
// combine x0 = (lam/NN)*sum_c conj(sm)*img + z ; x=0, r=p=x0 ; |x0|^2 partials ----
__global__ __launch_bounds__(512)
void setup_init(const c32* __restrict__ bufin, const c32* __restrict__ smaps,
                const c32* __restrict__ z, c32* __restrict__ x,
                c32* __restrict__ r, c32* __restrict__ p,
                const float* __restrict__ lam, float* __restrict__ part,
                const c32* __restrict__ T320, const c32* __restrict__ T64)
{
  __shared__ c32 tile[8][NN + 2];
  __shared__ float sredf[8];
  const int tid = threadIdx.x, lane = tid & 63, wv = tid >> 6;
  const int b = blockIdx.y, r0 = blockIdx.x * 8;
  LOAD_TWIDDLES
  const int rv6 = __brev((unsigned)lane) >> 26;
  const int w = r0 + wv;
  const float l0 = lam[0] * (1.f / (float)NN);
  c32 acc[NM][5];
  #pragma unroll
  for (int m = 0; m < NM; ++m)
    #pragma unroll
    for (int it = 0; it < 5; ++it) acc[m][it] = make_float2(0.f, 0.f);

  for (int c = 0; c < NC; ++c) {
    c32 A[5];
    #pragma unroll
    for (int j = 0; j < 5; ++j)
      A[j] = bufin[((size_t)(b*NC + c) * NN + w) * NN + lane + 64*j];
    fft320_one<false>(A, ct, tw, lane);   // natural kh -> scrambled h
    __syncthreads();                       // tile free from previous coil
    #pragma unroll
    for (int k = 0; k < 5; ++k) tile[wv][k + 5*rv6] = A[k];
    __syncthreads();
    #pragma unroll
    for (int it = 0; it < 5; ++it) {
      const int idx = it * 512 + tid, u = idx >> 3, d = idx & 7;
      c32 v = tile[d][u];
      #pragma unroll
      for (int m = 0; m < NM; ++m) {
        c32 s = smaps[(size_t)((b*NC + c)*NM + m) * NHW + (size_t)u * NN + (r0 + d)];
        acc[m][it] = cadd(acc[m][it], cmulj(s, v));
      }
    }
  }
  float accf = 0.f;
  #pragma unroll
  for (int it = 0; it < 5; ++it) {
    const int idx = it * 512 + tid, u = idx >> 3, d = idx & 7;
    #pragma unroll
    for (int m = 0; m < NM; ++m) {
      const size_t im = (size_t)(b*NM + m) * NHW + (size_t)u * NN + (r0 + d);
      c32 x0v = cadd(cscale(acc[m][it], l0), z[im]);
      x[im] = make_float2(0.f, 0.f);
      r[im] = x0v; p[im] = x0v;
      accf += x0v.x*x0v.x + x0v.y*x0v.y;
    }
  }
  accf = wave_reduce_f(accf);
  if (lane == 0) sredf[wv] = accf;
  __syncthreads();
  if (tid == 0) {
    float s = 0.f;
    #pragma unroll
    for (int k = 0; k < 8; ++k) s += sredf[k];
    part[b*CBLK + blockIdx.x] = s;
  }
}

__global__ void reduce_init(const float* __restrict__ part, float* __restrict__ x0x0,
                            float* __restrict__ rr0, float* __restrict__ flags)
{
  const int lane = threadIdx.x & 63;
  const int b = threadIdx.x >> 6;
  float s = 0.f;
  for (int j = lane; j < 40; j += 64) s += part[b*CBLK + j];
  s = wave_reduce_f(s);
  if (lane == 0) { x0x0[b] = s; rr0[b] = s; }
  if (threadIdx.x == 0) flags[0] = 1.f;
}

// ---- per-iter kernel 1: p_new = r + beta*p_prev; coil-combine (CPG coils); FFT_w; transposed write ----
__global__ __launch_bounds__(512)
void fft_comb_deep(c32* __restrict__ out, const c32* __restrict__ pin,
                   const c32* __restrict__ rres, c32* __restrict__ pout,
                   const c32* __restrict__ smaps,
                   const float* __restrict__ rr_prev, const float* __restrict__ rr_cur,
                   const float* __restrict__ flag,
                   const c32* __restrict__ T320, const c32* __restrict__ T64)
{
  if (flag[0] == 0.f) return;
  __shared__ c32 tile[8][NN + 2];
  const int tid = threadIdx.x, lane = tid & 63, wv = tid >> 6;
  const int by = blockIdx.y, b = by >> 2, g = by & 3;
  const int r0 = blockIdx.x * 8;
  const int row = r0 + wv;                  // image h row
  const bool upd = (rr_cur != nullptr);
  const float beta = upd ? rr_cur[b] / rr_prev[b] : 0.f;
  LOAD_TWIDDLES
  const int rv6 = __brev((unsigned)lane) >> 26;
  const size_t m0 = (size_t)(b*NM + 0) * NHW, m1 = (size_t)(b*NM + 1) * NHW;
  c32 p0[5], p1[5];
  #pragma unroll
  for (int j = 0; j < 5; ++j) {
    const size_t h = (size_t)row * NN + lane + 64*j;
    c32 r0v = rres[m0 + h], r1v = rres[m1 + h];
    if (upd) {
      p0[j] = cadd(r0v, cscale(pin[m0 + h], beta));
      p1[j] = cadd(r1v, cscale(pin[m1 + h], beta));
      if (g == 0) { pout[m0 + h] = p0[j]; pout[m1 + h] = p1[j]; }
    } else { p0[j] = r0v; p1[j] = r1v; }
  }
  for (int cc = 0; cc < CPG; ++cc) {
    const int c = g * CPG + cc;
    const size_t s0o = (size_t)((b*NC + c)*NM + 0) * NHW, s1o = (size_t)((b*NC + c)*NM + 1) * NHW;
    c32 A[5];
    #pragma unroll
    for (int j = 0; j < 5; ++j) {
      const size_t h = (size_t)row * NN + lane + 64*j;
      A[j] = cadd(cmul(p0[j], smaps[s0o + h]), cmul(p1[j], smaps[s1o + h]));
    }
    fft320_one<true>(A, ct, tw, lane);
    __syncthreads();
    #pragma unroll
    for (int k = 0; k < 5; ++k) tile[wv][k + 5*rv6] = A[k];
    __syncthreads();
    #pragma unroll
    for (int it = 0; it < 5; ++it) {
      const int idx = it * 512 + tid, u = idx >> 3, d = idx & 7;
      out[(size_t)(b*NC + c) * NHW + (size_t)u * NN + (r0 + d)] = tile[d][u];
    }
  }
}

// ---- per-iter kernel 2: FFT_h -> mask (scrambled) -> DIT-IFFT_h -> transposed write, CPG coils ----
__global__ __launch_bounds__(512)
void fmi_deep(const c32* __restrict__ in, c32* __restrict__ out,
              const float* __restrict__ mask, const float* __restrict__ flag,
              const c32* __restrict__ T320, const c32* __restrict__ T64)
{
  if (flag[0] == 0.f) return;
  __shared__ c32 tile[8][NN + 2];
  const int tid = threadIdx.x, lane = tid & 63, wv = tid >> 6;
  const int by = blockIdx.y, b = by >> 2, g = by & 3;
  const int r0 = blockIdx.x * 8;
  const int row = r0 + wv;                  // k_w row
  LOAD_TWIDDLES
  const int rv6 = __brev((unsigned)lane) >> 26;
  for (int cc = 0; cc < CPG; ++cc) {
    const int bc = b*NC + g*CPG + cc;
    c32 A[5];
    #pragma unroll
    for (int j = 0; j < 5; ++j)
      A[j] = in[((size_t)bc * NN + row) * NN + lane + 64*j];
    fft320_one<true>(A, ct, tw, lane);       // natural h -> scrambled kh
    #pragma unroll
    for (int k = 0; k < 5; ++k) {
      const int kh = k + 5*rv6;
      A[k] = cscale(A[k], mask[(size_t)bc * NHW + (size_t)kh * NN + row]);
    }
    ifft320_dit(A, ct, tw, lane);            // scrambled kh -> natural h
    __syncthreads();
    #pragma unroll
    for (int j = 0; j < 5; ++j) tile[wv][lane + 64*j] = A[j];
    __syncthreads();
    #pragma unroll
    for (int it = 0; it < 5; ++it) {
      const int idx = it * 512 + tid, u = idx >> 3, d = idx & 7;
      out[(size_t)bc * NHW + (size_t)u * NN + (r0 + d)] = tile[d][u];   // [bc][h][kw]
    }
  }
}

// ---- per-iter kernel 3: IFFT_w + coil-combine + q = (lam/NHW)*AT + p + pq partials.
// One 64-thread block (one wave) per (b, h-row); 12 coils with next-coil prefetch. ----
__global__ __launch_bounds__(64)
void ifft_q(const c32* __restrict__ bufin, const c32* __restrict__ smaps,
            const c32* __restrict__ p, c32* __restrict__ q,
            const float* __restrict__ lam, const float* __restrict__ flag,
            c32* __restrict__ pqpart,
            const c32* __restrict__ T320, const c32* __restrict__ T64)
{
  if (flag[0] == 0.f) return;
  __shared__ c32 tile[NN + 2];
  const int lane = threadIdx.x;
  const int b = blockIdx.y, h = blockIdx.x;
  LOAD_TWIDDLES
  const int rv6 = __brev((unsigned)lane) >> 26;
  const float lq = lam[0] * (1.f / (float)NHW);
  const size_t rowoff = (size_t)h * NN + lane;
  c32 acc0[5], acc1[5];
  #pragma unroll
  for (int j = 0; j < 5; ++j) { acc0[j] = make_float2(0.f,0.f); acc1[j] = make_float2(0.f,0.f); }
  c32 Ac[5], S0c[5], S1c[5];
  {
    const size_t ib  = (size_t)(b*NC) * NHW + rowoff;
    const size_t is0 = (size_t)((b*NC)*NM + 0) * NHW + rowoff;
    const size_t is1 = (size_t)((b*NC)*NM + 1) * NHW + rowoff;
    #pragma unroll
    for (int j = 0; j < 5; ++j) {
      Ac[j] = bufin[ib + 64*j]; S0c[j] = smaps[is0 + 64*j]; S1c[j] = smaps[is1 + 64*j];
    }
  }
  for (int c = 0; c < NC; ++c) {
    c32 An[5], S0n[5], S1n[5];
    if (c + 1 < NC) {                        // prefetch next coil before current FFT
      const size_t ib  = (size_t)(b*NC + c+1) * NHW + rowoff;
      const size_t is0 = (size_t)((b*NC + c+1)*NM + 0) * NHW + rowoff;
      const size_t is1 = (size_t)((b*NC + c+1)*NM + 1) * NHW + rowoff;
      #pragma unroll
      for (int j = 0; j < 5; ++j) {
        An[j] = bufin[ib + 64*j]; S0n[j] = smaps[is0 + 64*j]; S1n[j] = smaps[is1 + 64*j];
      }
    }
    fft320_one<false>(Ac, ct, tw, lane);     // natural kw -> scrambled w
    #pragma unroll
    for (int k = 0; k < 5; ++k) tile[k + 5*rv6] = Ac[k];
    __syncthreads();
    #pragma unroll
    for (int j = 0; j < 5; ++j) {
      c32 v = tile[lane + 64*j];
      acc0[j] = cadd(acc0[j], cmulj(S0c[j], v));
      acc1[j] = cadd(acc1[j], cmulj(S1c[j], v));
    }
    __syncthreads();
    if (c + 1 < NC) {
      #pragma unroll
      for (int j = 0; j < 5; ++j) { Ac[j]=An[j]; S0c[j]=S0n[j]; S1c[j]=S1n[j]; }
    }
  }
  const size_t i0 = (size_t)(b*NM + 0) * NHW + rowoff;
  const size_t i1 = (size_t)(b*NM + 1) * NHW + rowoff;
  c32 pqs = make_float2(0.f, 0.f);
  #pragma unroll
  for (int j = 0; j < 5; ++j) {
    c32 p0 = p[i0 + 64*j], p1 = p[i1 + 64*j];
    c32 q0 = cadd(cscale(acc0[j], lq), p0);
    c32 q1 = cadd(cscale(acc1[j], lq), p1);
    q[i0 + 64*j] = q0; q[i1 + 64*j] = q1;
    pqs = cadd(pqs, cadd(cmulj(q0, p0), cmulj(q1, p1)));
  }
  pqs = wave_reduce_c(pqs);
  if (lane == 0) pqpart[b*QBLK + blockIdx.x] = pqs;
}

// ---- per-iter kernel 4: re-reduce pq (deterministic) -> alpha; x += a p; r -= a q; |r|^2 partials ----
__global__ __launch_bounds__(256)
void update1(c32* __restrict__ x, c32* __restrict__ r,
             const c32* __restrict__ p, const c32* __restrict__ q,
             const float* __restrict__ rr_i, const c32* __restrict__ pqpart,
             const float* __restrict__ flag, float* __restrict__ part)
{
  if (flag[0] == 0.f) return;
  const int b = blockIdx.y;
  const int t = threadIdx.x;
  c32 s = make_float2(0.f, 0.f);
  for (int j = t; j < QBLK; j += 256) s = cadd(s, pqpart[b*QBLK + j]);
  s = wave_reduce_c(s);
  __shared__ c32 spq[4];
  const int lane = t & 63, wv = t >> 6;
  if (lane == 0) spq[wv] = s;
  __syncthreads();
  const c32 pqv = cadd(cadd(spq[0], spq[1]), cadd(spq[2], spq[3]));
  const float rrv = rr_i[b];
  const float den = pqv.x*pqv.x + pqv.y*pqv.y;
  const c32 alpha = make_float2(rrv * pqv.x / den, -rrv * pqv.y / den);
  const int hw = blockIdx.x * 256 + t;
  float acc = 0.f;
  #pragma unroll
  for (int m = 0; m < NM; ++m) {
    const size_t idx = (size_t)(b*NM + m) * NHW + hw;
    c32 pe = p[idx], qe = q[idx];
    c32 xe = cadd(x[idx], cmul(alpha, pe));
    c32 re = csub(r[idx], cmul(alpha, qe));
    x[idx] = xe; r[idx] = re;
    acc += re.x*re.x + re.y*re.y;
  }
  acc = wave_reduce_f(acc);
  __shared__ float sred[4];
  if (lane == 0) sred[wv] = acc;
  __syncthreads();
  if (t == 0) part[b*CBLK + blockIdx.x] = sred[0]+sred[1]+sred[2]+sred[3];
}

__global__ void reduce_rr(const float* __restrict__ part, const float* __restrict__ rr_i,
                          float* __restrict__ rr_n, const float* __restrict__ x0x0,
                          const float* __restrict__ flag_i, float* __restrict__ flag_n)
{
  const int lane = threadIdx.x & 63;
  const int b = threadIdx.x >> 6;
  __shared__ float sred[4];
  __shared__ float sx0[4];
  if (flag_i[0] == 0.f) {
    if (lane == 0) rr_n[b] = rr_i[b];
    if (threadIdx.x == 0) flag_n[0] = 0.f;
    return;
  }
  float s = 0.f;
  for (int j = lane; j < CBLK; j += 64) s += part[b*CBLK + j];
  s = wave_reduce_f(s);
  if (lane == 0) { rr_n[b] = s; sred[b] = s; sx0[b] = x0x0[b]; }
  __syncthreads();
  if (threadIdx.x == 0) {
    float mn = 1e30f;
    #pragma unroll
    for (int bb = 0; bb < NB; ++bb) mn = fminf(mn, sred[bb] / sx0[bb]);
    flag_n[0] = (mn > CG_TOL) ? 1.f : 0.f;
  }
}

extern "C" void kernel_launch(void* const* d_in, const int* in_sizes, int n_in,
                              void* d_out, int out_size, void* d_ws, size_t ws_size,
                              hipStream_t stream)
{
  const c32*  z   = (const c32*)d_in[0];
  const c32*  y   = (const c32*)d_in[1];
  const c32*  sm  = (const c32*)d_in[2];
  const float* mk = (const float*)d_in[3];
  const float* lam= (const float*)d_in[4];
  c32* x = (c32*)d_out;

  char* base = (char*)d_ws;
  size_t off = 0;
  auto walloc = [&](size_t bytes) -> void* {
    void* ptr = base + off;
    off += (bytes + 255) & ~(size_t)255;
    return ptr;
  };
  c32* buf1   = (c32*)walloc((size_t)NBC * NHW * sizeof(c32));
  c32* buf2   = (c32*)walloc((size_t)NBC * NHW * sizeof(c32));
  c32* rv     = (c32*)walloc((size_t)NB * NM * NHW * sizeof(c32));
  c32* pvA    = (c32*)walloc((size_t)NB * NM * NHW * sizeof(c32));
  c32* pvB    = (c32*)walloc((size_t)NB * NM * NHW * sizeof(c32));
  c32* qv     = (c32*)walloc((size_t)NB * NM * NHW * sizeof(c32));
  c32* pqpart = (c32*)walloc((size_t)NB * QBLK * sizeof(c32));
  float* x0x0 = (float*)walloc(NB * sizeof(float));
  float* rr   = (float*)walloc((NITER + 1) * NB * sizeof(float));
  float* flags= (float*)walloc((NITER + 1) * sizeof(float));
  float* part1= (float*)walloc((size_t)NB * CBLK * sizeof(float));
  c32* T320   = (c32*)walloc(256 * sizeof(c32));
  c32* T64    = (c32*)walloc(32 * sizeof(c32));
  (void)ws_size; (void)in_sizes; (void)n_in; (void)out_size;

  dim3 blk512(512), blk256(256), blk64(64);
  dim3 sgrid1(NN / 8, NBC);          // setup pass1: per (bc, kw-octet)
  dim3 sgrid2(NN / 8, NB);           // setup fused init: per (b, w-octet)
  dim3 dgrid(NN / 8, NB * NG);       // deep fft kernels: per (b, group, row-octet)
  dim3 qgrid(QBLK, NB);              // ifft_q: per (b, h-row)
  dim3 ugrid(CBLK, NB);

  twiddle_init<<<1, blk256, 0, stream>>>(T320, T64);

  // ---- setup ----
  setup_mask_ifft<<<sgrid1, blk512, 0, stream>>>(y, buf2, mk, T320, T64);
  setup_init<<<sgrid2, blk512, 0, stream>>>(buf2, sm, z, x, rv, pvA, lam, part1, T320, T64);
  reduce_init<<<1, blk256, 0, stream>>>(part1, x0x0, rr, flags);

  // ---- 10 CG iterations (5 kernels each) ----
  for (int i = 0; i < NITER; ++i) {
    const float* fl = flags + i;
    c32* pin  = (i & 1) ? pvA : pvB;
    c32* pout = (i & 1) ? pvB : pvA;
    const float* rrprev = (i > 0) ? (rr + (i-1)*NB) : rr;
    const float* rrcur  = (i > 0) ? (rr + i*NB) : nullptr;
    fft_comb_deep<<<dgrid, blk512, 0, stream>>>(buf2, pin, rv, pout, sm, rrprev, rrcur, fl, T320, T64);
    fmi_deep<<<dgrid, blk512, 0, stream>>>(buf2, buf1, mk, fl, T320, T64);
    ifft_q<<<qgrid, blk64, 0, stream>>>(buf1, sm, pout, qv, lam, fl, pqpart, T320, T64);
    update1<<<ugrid, blk256, 0, stream>>>(x, rv, pout, qv, rr + i*NB, pqpart, fl, part1);
    reduce_rr<<<1, blk256, 0, stream>>>(part1, rr + i*NB, rr + (i+1)*NB, x0x0, fl, flags + (i+1));
  }
}